// Round 1
// baseline (69.018 us; speedup 1.0000x reference)
//
#include <hip/hip_runtime.h>
#include <hip/hip_bf16.h>

#define BATCH   1024
#define IN_DIM  256
#define UNITS   256

// Uniform grid: g_m = -2.2 + 0.4*m, m = 0..11, h = 0.4.
// For x in [g_j, g_{j+1}), the 4 nonzero cubic B-spline bases (k = j-3..j):
//   b0=(1-t)^3/6, b1=(3t^3-6t^2+4)/6, b2=(-3t^3+3t^2+3t+1)/6, b3=t^3/6, t=(x-g_j)/h

__global__ __launch_bounds__(256) void kan_fused(
    const float* __restrict__ X,    // [1024][256]
    const float* __restrict__ SK,   // [256][8][256]
    const float* __restrict__ SF,   // [256][256]
    const float* __restrict__ BIAS, // [256]
    float* __restrict__ OUT)        // [1024][256]
{
    __shared__ float feat[128][12];   // [ii*4+r][k], k=0..7 bases, 8=silu, 9..11 pad
    const int tid  = threadIdx.x;
    const int brow = blockIdx.x * 4;
    const int o    = tid;

    float acc[4] = {0.f, 0.f, 0.f, 0.f};

    for (int c = 0; c < 8; ++c) {
        if (tid < 128) {
            const int ii = tid >> 2;
            const int r  = tid & 3;
            const int i  = c * 32 + ii;
            const float x = X[(size_t)(brow + r) * IN_DIM + i];
            float u = (x + 2.2f) * 2.5f;            // (x - (-2.2)) / 0.4
            int j = (int)floorf(u);
            j = j < 3 ? 3 : (j > 7 ? 7 : j);
            const float gj = -2.2f + 0.4f * (float)j;
            const float t  = (x - gj) * 2.5f;
            const float t2 = t * t, t3 = t2 * t;
            const float k6 = 1.f / 6.f;
            const float b0 = (1.f - 3.f*t + 3.f*t2 - t3) * k6;
            const float b1 = (3.f*t3 - 6.f*t2 + 4.f) * k6;
            const float b2 = (-3.f*t3 + 3.f*t2 + 3.f*t + 1.f) * k6;
            const float b3 = t3 * k6;
            float* fp = feat[ii * 4 + r];
            #pragma unroll
            for (int k = 0; k < 12; ++k) fp[k] = 0.f;
            const int base = j - 3;                  // 0..4
            fp[base + 0] = b0;
            fp[base + 1] = b1;
            fp[base + 2] = b2;
            fp[base + 3] = b3;
            fp[8] = x / (1.f + __expf(-x));          // silu
        }
        __syncthreads();

        #pragma unroll 4
        for (int ii = 0; ii < 32; ++ii) {
            const int i = c * 32 + ii;
            const float* skp = SK + (size_t)i * 8 * UNITS + o;
            const float s0 = skp[0 * UNITS], s1 = skp[1 * UNITS];
            const float s2 = skp[2 * UNITS], s3 = skp[3 * UNITS];
            const float s4 = skp[4 * UNITS], s5 = skp[5 * UNITS];
            const float s6 = skp[6 * UNITS], s7 = skp[7 * UNITS];
            const float sfv = SF[(size_t)i * UNITS + o];
            #pragma unroll
            for (int r = 0; r < 4; ++r) {
                const float* fp = feat[ii * 4 + r];
                const float4 fa = *(const float4*)(fp);
                const float4 fb = *(const float4*)(fp + 4);
                const float f8 = fp[8];
                float ts = f8;
                ts = fmaf(fa.x, s0, ts);
                ts = fmaf(fa.y, s1, ts);
                ts = fmaf(fa.z, s2, ts);
                ts = fmaf(fa.w, s3, ts);
                ts = fmaf(fb.x, s4, ts);
                ts = fmaf(fb.y, s5, ts);
                ts = fmaf(fb.z, s6, ts);
                ts = fmaf(fb.w, s7, ts);
                acc[r] = fmaf(sfv, ts, acc[r]);
            }
        }
        __syncthreads();
    }

    const float bo = BIAS[o];
    #pragma unroll
    for (int r = 0; r < 4; ++r) {
        OUT[(size_t)(brow + r) * UNITS + o] = acc[r] + bo;
    }
}

extern "C" void kernel_launch(void* const* d_in, const int* in_sizes, int n_in,
                              void* d_out, int out_size, void* d_ws, size_t ws_size,
                              hipStream_t stream) {
    const float* X  = (const float*)d_in[0];
    const float* SK = (const float*)d_in[1];
    const float* SF = (const float*)d_in[2];
    const float* B  = (const float*)d_in[3];
    float* OUT = (float*)d_out;
    kan_fused<<<dim3(BATCH / 4), dim3(256), 0, stream>>>(X, SK, SF, B, OUT);
}

// Round 2
// 19.853 us; speedup vs baseline: 3.4765x; 3.4765x over previous
//
#include <hip/hip_runtime.h>
#include <hip/hip_bf16.h>

#define BATCH   1024
#define IN_DIM  256
#define UNITS   256

using short8 = __attribute__((ext_vector_type(8))) short;
using f32x4  = __attribute__((ext_vector_type(4))) float;

// A_p: [mt=64][s=72][lane=64][e=8] bf16   (M=1024 rows /16, K=2304 /32)
// W_p: [nt=16][s=72][lane=64][e=8] bf16   (N=256 cols /16)
#define A_ELEMS (64 * 72 * 512)   // 2,359,296 ushort
#define W_ELEMS (16 * 72 * 512)   //   589,824 ushort

__device__ __forceinline__ unsigned short f2bf(float v) {
    __hip_bfloat16 h = __float2bfloat16(v);
    return *reinterpret_cast<unsigned short*>(&h);
}

// ---------------- prep A: features -> fragment-packed bf16 -------------
// grid 256 = (mt 64) x (quarter q 4); each block: rows mt*16..+16, i in [64q,64q+64)
__global__ __launch_bounds__(256) void prep_a(const float* __restrict__ X,
                                              unsigned short* __restrict__ Ap) {
    __shared__ unsigned short tile[18 * 512];   // 18 K-steps of this quarter
    const int mt = blockIdx.x >> 2;
    const int q  = blockIdx.x & 3;
    const int t  = threadIdx.x;

    #pragma unroll
    for (int rr = 0; rr < 4; ++rr) {
        const int p  = t + 256 * rr;
        const int b  = p >> 6;          // 0..15 row in tile
        const int il = p & 63;          // 0..63 local i
        const int i  = q * 64 + il;
        const float x = X[(mt * 16 + b) * IN_DIM + i];
        const float u = (x + 2.2f) * 2.5f;
        int j = (int)floorf(u);
        j = j < 3 ? 3 : (j > 7 ? 7 : j);
        const float gj = -2.2f + 0.4f * (float)j;
        const float tt = (x - gj) * 2.5f;
        const float t2 = tt * tt, t3 = t2 * tt;
        const float k6 = 1.f / 6.f;
        const float b0 = (1.f - 3.f * tt + 3.f * t2 - t3) * k6;
        const float b1 = (3.f * t3 - 6.f * t2 + 4.f) * k6;
        const float b2 = (-3.f * t3 + 3.f * t2 + 3.f * tt + 1.f) * k6;
        const float b3 = t3 * k6;
        const float sil = x / (1.f + __expf(-x));
        const int base = j - 3;          // 0..4
        const int kk0  = il * 9;
        #pragma unroll
        for (int kf = 0; kf < 9; ++kf) {
            float v;
            if (kf == 8) v = sil;
            else v = (kf == base)     ? b0
                   : (kf == base + 1) ? b1
                   : (kf == base + 2) ? b2
                   : (kf == base + 3) ? b3 : 0.f;
            const int kkl  = kk0 + kf;           // local kk within quarter (576)
            const int sl   = kkl >> 5;           // 0..17
            const int kpos = kkl & 31;
            tile[sl * 512 + ((b | ((kpos >> 3) << 4)) << 3) + (kpos & 7)] = f2bf(v);
        }
    }
    __syncthreads();
    const unsigned int* src = (const unsigned int*)tile;
    unsigned int* dst = (unsigned int*)Ap + (mt * 72 + 18 * q) * 256;
    #pragma unroll
    for (int k = 0; k < 18; ++k) dst[t + 256 * k] = src[t + 256 * k];
}

// ---------------- prep W: sk*sf (k<8), sf (k=8) -> fragment-packed -----
// one thread per 16B slot; grid 288 x 256
__global__ __launch_bounds__(256) void prep_w(const float* __restrict__ SK,
                                              const float* __restrict__ SF,
                                              unsigned short* __restrict__ Wp) {
    const int slot = blockIdx.x * 256 + threadIdx.x;   // < 73728
    const int lane = slot & 63;
    const int s    = (slot >> 6) % 72;
    const int nt   = slot / (72 * 64);
    const int o    = nt * 16 + (lane & 15);
    const int kb   = (lane >> 4) << 3;
    unsigned short r[8];
    #pragma unroll
    for (int e = 0; e < 8; ++e) {
        const int kk = s * 32 + kb + e;   // 0..2303
        const int i  = kk / 9;
        const int kf = kk - i * 9;
        const float sfv = SF[i * UNITS + o];
        const float v = (kf < 8) ? SK[(i * 8 + kf) * UNITS + o] * sfv : sfv;
        r[e] = f2bf(v);
    }
    unsigned int pack[4];
    #pragma unroll
    for (int e = 0; e < 4; ++e)
        pack[e] = (unsigned int)r[2 * e] | ((unsigned int)r[2 * e + 1] << 16);
    reinterpret_cast<uint4*>(Wp)[slot] = make_uint4(pack[0], pack[1], pack[2], pack[3]);
}

// ---------------- GEMM: 256 blocks x 512 thr; tile 32x32, K split 8 ----
__global__ __launch_bounds__(512) void kan_gemm(const unsigned short* __restrict__ Ap,
                                                const unsigned short* __restrict__ Wp,
                                                const float* __restrict__ BIAS,
                                                float* __restrict__ OUT) {
    __shared__ float red[8 * 1024];    // 32 KB: [wave][frag4][lane][4]
    const int tid  = threadIdx.x;
    const int w    = tid >> 6;
    const int lane = tid & 63;
    const int m = blockIdx.x & 31;     // M-tile (32 rows); XCD-friendly: same-XCD shares m set
    const int n = blockIdx.x >> 5;     // N-tile (32 cols)
    const short8* A8 = (const short8*)Ap;
    const short8* W8 = (const short8*)Wp;
    const int mt0 = 2 * m, nt0 = 2 * n;
    const int s0  = 9 * w;

    const short8* pa0 = A8 + (size_t)(mt0 * 72 + s0) * 64 + lane;
    const short8* pa1 = pa0 + 72 * 64;
    const short8* pb0 = W8 + (size_t)(nt0 * 72 + s0) * 64 + lane;
    const short8* pb1 = pb0 + 72 * 64;

    f32x4 acc00 = {0.f, 0.f, 0.f, 0.f}, acc01 = {0.f, 0.f, 0.f, 0.f};
    f32x4 acc10 = {0.f, 0.f, 0.f, 0.f}, acc11 = {0.f, 0.f, 0.f, 0.f};

    short8 a0 = pa0[0], a1 = pa1[0], b0 = pb0[0], b1 = pb1[0];
    #pragma unroll
    for (int it = 0; it < 9; ++it) {
        acc00 = __builtin_amdgcn_mfma_f32_16x16x32_bf16(a0, b0, acc00, 0, 0, 0);
        acc01 = __builtin_amdgcn_mfma_f32_16x16x32_bf16(a0, b1, acc01, 0, 0, 0);
        acc10 = __builtin_amdgcn_mfma_f32_16x16x32_bf16(a1, b0, acc10, 0, 0, 0);
        acc11 = __builtin_amdgcn_mfma_f32_16x16x32_bf16(a1, b1, acc11, 0, 0, 0);
        if (it < 8) {
            a0 = pa0[64 * (it + 1)];
            a1 = pa1[64 * (it + 1)];
            b0 = pb0[64 * (it + 1)];
            b1 = pb1[64 * (it + 1)];
        }
    }

    f32x4* redv = (f32x4*)red;
    redv[(w * 4 + 0) * 64 + lane] = acc00;   // frag f = mt_loc*2 + nt_loc
    redv[(w * 4 + 1) * 64 + lane] = acc01;
    redv[(w * 4 + 2) * 64 + lane] = acc10;
    redv[(w * 4 + 3) * 64 + lane] = acc11;
    __syncthreads();

    #pragma unroll
    for (int half = 0; half < 2; ++half) {
        const int flat = half * 512 + tid;     // 0..1023
        float sum = 0.f;
        #pragma unroll
        for (int w2 = 0; w2 < 8; ++w2) sum += red[w2 * 1024 + flat];
        const int f  = flat >> 8;
        const int l  = (flat >> 2) & 63;
        const int rr = flat & 3;
        const int row = m * 32 + (f >> 1) * 16 + ((l >> 4) << 2) + rr;
        const int col = n * 32 + (f & 1) * 16 + (l & 15);
        OUT[row * UNITS + col] = sum + BIAS[col];
    }
}

// ---------------- fallback (round-1 fused fp32) ------------------------
__global__ __launch_bounds__(256) void kan_fused(
    const float* __restrict__ X, const float* __restrict__ SK,
    const float* __restrict__ SF, const float* __restrict__ BIAS,
    float* __restrict__ OUT) {
    __shared__ float feat[128][12];
    const int tid  = threadIdx.x;
    const int brow = blockIdx.x * 4;
    const int o    = tid;
    float acc[4] = {0.f, 0.f, 0.f, 0.f};
    for (int c = 0; c < 8; ++c) {
        if (tid < 128) {
            const int ii = tid >> 2;
            const int r  = tid & 3;
            const int i  = c * 32 + ii;
            const float x = X[(size_t)(brow + r) * IN_DIM + i];
            float u = (x + 2.2f) * 2.5f;
            int j = (int)floorf(u);
            j = j < 3 ? 3 : (j > 7 ? 7 : j);
            const float gj = -2.2f + 0.4f * (float)j;
            const float t  = (x - gj) * 2.5f;
            const float t2 = t * t, t3 = t2 * t;
            const float k6 = 1.f / 6.f;
            float* fp = feat[ii * 4 + r];
            #pragma unroll
            for (int k = 0; k < 12; ++k) fp[k] = 0.f;
            const int base = j - 3;
            fp[base + 0] = (1.f - 3.f*t + 3.f*t2 - t3) * k6;
            fp[base + 1] = (3.f*t3 - 6.f*t2 + 4.f) * k6;
            fp[base + 2] = (-3.f*t3 + 3.f*t2 + 3.f*t + 1.f) * k6;
            fp[base + 3] = t3 * k6;
            fp[8] = x / (1.f + __expf(-x));
        }
        __syncthreads();
        #pragma unroll 4
        for (int ii = 0; ii < 32; ++ii) {
            const int i = c * 32 + ii;
            const float* skp = SK + (size_t)i * 8 * UNITS + o;
            const float s0 = skp[0*UNITS], s1 = skp[1*UNITS], s2 = skp[2*UNITS], s3 = skp[3*UNITS];
            const float s4 = skp[4*UNITS], s5 = skp[5*UNITS], s6 = skp[6*UNITS], s7 = skp[7*UNITS];
            const float sfv = SF[(size_t)i * UNITS + o];
            #pragma unroll
            for (int r = 0; r < 4; ++r) {
                const float* fp = feat[ii * 4 + r];
                const float4 fa = *(const float4*)(fp);
                const float4 fb = *(const float4*)(fp + 4);
                float ts = fp[8];
                ts = fmaf(fa.x, s0, ts); ts = fmaf(fa.y, s1, ts);
                ts = fmaf(fa.z, s2, ts); ts = fmaf(fa.w, s3, ts);
                ts = fmaf(fb.x, s4, ts); ts = fmaf(fb.y, s5, ts);
                ts = fmaf(fb.z, s6, ts); ts = fmaf(fb.w, s7, ts);
                acc[r] = fmaf(sfv, ts, acc[r]);
            }
        }
        __syncthreads();
    }
    const float bo = BIAS[o];
    #pragma unroll
    for (int r = 0; r < 4; ++r)
        OUT[(size_t)(brow + r) * UNITS + o] = acc[r] + bo;
}

extern "C" void kernel_launch(void* const* d_in, const int* in_sizes, int n_in,
                              void* d_out, int out_size, void* d_ws, size_t ws_size,
                              hipStream_t stream) {
    const float* X  = (const float*)d_in[0];
    const float* SK = (const float*)d_in[1];
    const float* SF = (const float*)d_in[2];
    const float* B  = (const float*)d_in[3];
    float* OUT = (float*)d_out;

    const size_t need = ((size_t)A_ELEMS + (size_t)W_ELEMS) * 2;   // 5,898,240 B
    if (d_ws != nullptr && ws_size >= need) {
        unsigned short* Ap = (unsigned short*)d_ws;
        unsigned short* Wp = Ap + A_ELEMS;
        prep_a<<<dim3(256), dim3(256), 0, stream>>>(X, Ap);
        prep_w<<<dim3(288), dim3(256), 0, stream>>>(SK, SF, Wp);
        kan_gemm<<<dim3(256), dim3(512), 0, stream>>>(Ap, Wp, B, OUT);
    } else {
        kan_fused<<<dim3(BATCH / 4), dim3(256), 0, stream>>>(X, SK, SF, B, OUT);
    }
}